// Round 20
// baseline (28.957 us; speedup 1.0000x reference)
//
#include <hip/hip_runtime.h>
#include <float.h>

#define MM 256
#define PP 2097152            // fixed pair-list length
#define NBLK 512              // 512 slots: 128 structures x 4 row-blocks
#define CBLK 256              // count grid: 128 structures x 2 half-blocks
#define GTH (NBLK * 256)
// Largest fp32 sq with rn(sqrt(sq)) < 5.0f  (== 25 - 2*ulp(25); boundary-exact)
#define SQMAX 24.999996185302734375f

typedef unsigned long long u64;

// ws layout: masks u64[GTH] | bsums int[NBLK] | minvec float[3]

__device__ inline void wave_min3(float& x, float& y, float& z) {
    #pragma unroll
    for (int off = 32; off > 0; off >>= 1) {
        x = fminf(x, __shfl_xor(x, off, 64));
        y = fminf(y, __shfl_xor(y, off, 64));
        z = fminf(z, __shfl_xor(z, off, 64));
    }
}

__device__ inline void zero_range(float* __restrict__ o, int lo, int hi, int g) {
    int a = (lo + 3) & ~3;           // hi is always a multiple of 4
    if (a > hi) a = hi;
    if (g < a - lo) o[lo + g] = 0.0f;
    float4* o4 = reinterpret_cast<float4*>(o);
    const float4 z4 = make_float4(0.f, 0.f, 0.f, 0.f);
    for (int q = (a >> 2) + g; q < (hi >> 2); q += GTH) o4[q] = z4;
}

// ---------------------------------------------------------------------------
// Geometry: slot b2 = b*4+rblk covers rows rblk*64..+64 of structure b;
// slot-thread tt = i_loc*4+c handles (row i_loc, j-chunk c); global slot
// b2*256+tt is lexicographic in (b,i,j). fp32 replicates the reference
// exactly: pos=coord-min (rn sub), diff=pos_j-pos_i, sq=((dx*dx+dy*dy)+dz*dz)
// no-FMA; membership sq<=SQMAX (== rn(sqrt(sq))<5 exactly); d=rn(sqrt) for
// hits only. fmin exact & order-independent -> matches jnp.min bitwise.
// ---------------------------------------------------------------------------

// K1 (256 blocks x 512 thr): stride-1 redundant global min (+%3 demux), then
// count with UNROLLED distance loop (ILP across ds_reads) -> masks, bsums.
__global__ void __launch_bounds__(512)
count_k(const float* __restrict__ coord, float* __restrict__ minvec,
        u64* __restrict__ masks, int* __restrict__ bsums) {
    const int cb = blockIdx.x;           // structure b = cb>>1, half = cb&1
    const int b = cb >> 1, h = cb & 1;
    const int t = threadIdx.x;           // 0..511
    const int lane = t & 63, w = t >> 6; // w 0..7

    __shared__ float4 tile4[4][65];
    __shared__ float lmin[3][8];
    __shared__ int wsum[8];

    // redundant global min over 24576 float4s, perfectly coalesced;
    // comp(f.x)=comp(f.w)=j%3, comp(f.y)=(j+1)%3, comp(f.z)=(j+2)%3.
    const float4* c4 = reinterpret_cast<const float4*>(coord);
    float mx = FLT_MAX, my = FLT_MAX, mz = FLT_MAX;
    int r = t % 3;
    #pragma unroll 6
    for (int k = 0; k < 48; ++k) {
        const float4 f = c4[k * 512 + t];
        const float p = fminf(f.x, f.w);
        const float vx = (r == 0) ? p : ((r == 1) ? f.z : f.y);
        const float vy = (r == 1) ? p : ((r == 0) ? f.y : f.z);
        const float vz = (r == 2) ? p : ((r == 0) ? f.z : f.y);
        mx = fminf(mx, vx);
        my = fminf(my, vy);
        mz = fminf(mz, vz);
        r += 2; if (r >= 3) r -= 3;       // (j+512)%3 : 512 ≡ 2 (mod 3)
    }
    wave_min3(mx, my, mz);
    if (lane == 0) { lmin[0][w] = mx; lmin[1][w] = my; lmin[2][w] = mz; }
    __syncthreads();
    mx = fminf(fminf(fminf(lmin[0][0], lmin[0][1]), fminf(lmin[0][2], lmin[0][3])),
               fminf(fminf(lmin[0][4], lmin[0][5]), fminf(lmin[0][6], lmin[0][7])));
    my = fminf(fminf(fminf(lmin[1][0], lmin[1][1]), fminf(lmin[1][2], lmin[1][3])),
               fminf(fminf(lmin[1][4], lmin[1][5]), fminf(lmin[1][6], lmin[1][7])));
    mz = fminf(fminf(fminf(lmin[2][0], lmin[2][1]), fminf(lmin[2][2], lmin[2][3])),
               fminf(fminf(lmin[2][4], lmin[2][5]), fminf(lmin[2][6], lmin[2][7])));
    if (cb == 0 && t == 0) { minvec[0] = mx; minvec[1] = my; minvec[2] = mz; }

    // stage the whole structure's tile (shifted); threads 0..255
    if (t < 256) {
        const int ja = b * MM + t;
        tile4[t >> 6][t & 63] = make_float4(__fsub_rn(coord[3 * ja + 0], mx),
                                            __fsub_rn(coord[3 * ja + 1], my),
                                            __fsub_rn(coord[3 * ja + 2], mz), 0.0f);
    }
    __syncthreads();

    // count: hit bitmask (slot = cb*512 + t, lexicographic); UNROLLED for ILP
    const int rblk = 2 * h + (t >> 8);
    const int tt = t & 255;
    const int i_loc = tt >> 2, c = tt & 3;
    const float4 pi4 = tile4[rblk][i_loc];
    u64 m = 0ULL;
    #pragma unroll 8
    for (int jj = 0; jj < 64; ++jj) {
        float4 v = tile4[c][jj];
        float dx = __fsub_rn(v.x, pi4.x);
        float dy = __fsub_rn(v.y, pi4.y);
        float dz = __fsub_rn(v.z, pi4.z);
        float sq = __fadd_rn(__fadd_rn(__fmul_rn(dx, dx), __fmul_rn(dy, dy)),
                             __fmul_rn(dz, dz));
        if (sq > 0.0f && sq <= SQMAX) m |= (1ULL << jj);
    }
    masks[cb * 512 + t] = m;

    int v = __popcll(m);
    #pragma unroll
    for (int off = 32; off > 0; off >>= 1) v += __shfl_xor(v, off, 64);
    if (lane == 0) wsum[w] = v;
    __syncthreads();
    if (t == 0) {
        bsums[cb * 2 + 0] = wsum[0] + wsum[1] + wsum[2] + wsum[3];
        bsums[cb * 2 + 1] = wsum[4] + wsum[5] + wsum[6] + wsum[7];
    }
}

// K2 (512 blocks x 256 thr): RANK-REDISTRIBUTED emit. Thread k handles the
// block's k-th pair: binary-search the owning thread in thrOff[257], select
// its r-th set bit, recompute, store directly at base+k (d: coalesced dword;
// ind2: aligned float2; df: 3 dword streams, lines fully covered per wave).
// No staging planes, no batches, one barrier; ~10 KB LDS -> high occupancy.
__global__ void __launch_bounds__(256)
write_k(const float* __restrict__ coord, const float* __restrict__ minvec,
        const u64* __restrict__ masks, const int* __restrict__ bsums,
        float* __restrict__ outF) {
    const int b2 = blockIdx.x;
    const int b = b2 >> 2, rblk = b2 & 3;
    const int t = threadIdx.x;
    const int lane = t & 63, w = t >> 6;

    __shared__ float4 tile4[4][65];
    __shared__ int pre[NBLK];
    __shared__ int sTot;
    __shared__ int wsum[4];
    __shared__ u64 smask[256];
    __shared__ int thrOff[257];

    const u64 mask = masks[b2 * 256 + t];              // issue early
    smask[t] = mask;
    const float mnx = minvec[0], mny = minvec[1], mnz = minvec[2];
    const int ja = b * MM + t;
    tile4[w][lane] = make_float4(__fsub_rn(coord[3 * ja + 0], mnx),
                                 __fsub_rn(coord[3 * ja + 1], mny),
                                 __fsub_rn(coord[3 * ja + 2], mnz), 0.0f);

    // wave-0 register scan of the 512 block sums (single barrier)
    if (w == 0) {
        int v[8]; int s = 0;
        #pragma unroll
        for (int q = 0; q < 8; ++q) { v[q] = bsums[lane * 8 + q]; s += v[q]; }
        int isum = s;
        #pragma unroll
        for (int off = 1; off < 64; off <<= 1) {
            int u = __shfl_up(isum, off, 64);
            if (lane >= off) isum += u;
        }
        int run = isum - s;                       // exclusive prefix, lane-major
        #pragma unroll
        for (int q = 0; q < 8; ++q) { pre[lane * 8 + q] = run; run += v[q]; }
        if (lane == 63) sTot = run;               // grand total
    }

    // per-thread exclusive offsets within the block -> thrOff
    const int cnt = __popcll(mask);
    int incl = cnt;
    #pragma unroll
    for (int off = 1; off < 64; off <<= 1) {
        int v = __shfl_up(incl, off, 64);
        if (lane >= off) incl += v;
    }
    if (lane == 63) wsum[w] = incl;
    __syncthreads();
    int woff = 0;
    for (int k = 0; k < w; ++k) woff += wsum[k];
    thrOff[t] = woff + incl - cnt;
    if (t == 255) thrOff[256] = woff + incl;      // == agg
    __syncthreads();

    const int base = pre[b2];
    const int agg = thrOff[256];
    const int total = (sTot < PP) ? sTot : PP;

    // rank-redistributed emission: k-th pair of this block
    for (int k = t; k < agg; k += 256) {
        const int p = base + k;
        if (p >= PP) break;
        // binary search: largest u with thrOff[u] <= k
        int lo = 0, hi = 256;
        #pragma unroll
        for (int s = 0; s < 8; ++s) {
            const int mid = (lo + hi) >> 1;
            if (thrOff[mid] <= k) lo = mid; else hi = mid;
        }
        const int u = lo;
        int r = k - thrOff[u];
        u64 mm = smask[u];
        while (r--) mm &= mm - 1;                 // drop r lowest set bits
        const int jj = __ffsll((long long)mm) - 1;

        const int iu = u >> 2, cu = u & 3;
        const float4 pi4 = tile4[rblk][iu];
        const float4 v = tile4[cu][jj];
        const float dx = __fsub_rn(v.x, pi4.x);
        const float dy = __fsub_rn(v.y, pi4.y);
        const float dz = __fsub_rn(v.z, pi4.z);
        const float sq = __fadd_rn(__fadd_rn(__fmul_rn(dx, dx), __fmul_rn(dy, dy)),
                                   __fmul_rn(dz, dz));
        outF[2 * PP + p] = __fsqrt_rn(sq);
        float2 ind2 = make_float2((float)(b * MM + rblk * 64 + iu),
                                  (float)(b * MM + cu * 64 + jj));
        *reinterpret_cast<float2*>(outF + 2 * p) = ind2;   // 8B-aligned
        const int dfb = 3 * PP + 3 * p;
        outF[dfb + 0] = dx;
        outF[dfb + 1] = dy;
        outF[dfb + 2] = dz;
    }

    // tail zeroing (disjoint from pair region; coalesced float4)
    const int g = b2 * 256 + t;
    zero_range(outF, 2 * total,          2 * PP, g);
    zero_range(outF, 2 * PP + total,     3 * PP, g);
    zero_range(outF, 3 * PP + 3 * total, 6 * PP, g);
}

extern "C" void kernel_launch(void* const* d_in, const int* in_sizes, int n_in,
                              void* d_out, int out_size, void* d_ws, size_t ws_size,
                              hipStream_t stream) {
    const float* coord = (const float*)d_in[0];
    // d_in[1] (ind_1) structurally encoded (B contiguous blocks of M); unused.
    float* outF = (float*)d_out;

    u64*   masks  = (u64*)d_ws;                    // GTH u64 = 1 MB
    int*   bsums  = (int*)(masks + GTH);           // 512 ints
    float* minvec = (float*)(bsums + NBLK);        // 3 floats

    count_k<<<CBLK, 512, 0, stream>>>(coord, minvec, masks, bsums);
    write_k<<<NBLK, 256, 0, stream>>>(coord, minvec, masks, bsums, outF);
}